// Round 14
// baseline (147.311 us; speedup 1.0000x reference)
//
#include <hip/hip_runtime.h>
#include <stdint.h>
#include <math.h>

#define BDIM   2
#define CDIM   16
#define INS    64
#define OUTS   20
#define NPTS   8000          // 20^3
#define TOTN   (BDIM*NPTS)   // 16000

using f64x4 = __attribute__((ext_vector_type(4))) double;

#define MFMA64(a, b, c) __builtin_amdgcn_mfma_f64_16x16x4f64((a), (b), (c), 0, 0, 0)

// ---------------- ws layout (bytes, all 8B-aligned) ----------------
// sfeat(-2x): 0        +2,048,000   (B,N,C) f64, pre-scaled by -2
// tfeat     : 2048000  +2,048,000   (B,N,C) f64
// t2        : 4096000  +128,000     (B,N)   f64
// pscore    : 4224000  +B*nchunk*N*8
// pidx      : ...      +B*nchunk*N*4
// lpart     : ...      +504
// ~9.03 MB at nchunk=25 (proven to fit)

// Separable trilinear resize 64^3 -> 20^3 (jax.image.resize trilinear,
// antialias=True). Verified in round 13 (absmax 0.0, ~20 us). Unchanged.
__global__ __launch_bounds__(256) void k_resize(const float* __restrict__ src,
                                                const float* __restrict__ tgt,
                                                double* __restrict__ sfeat2,
                                                double* __restrict__ tfeat) {
    __shared__ double wts[OUTS][8];
    __shared__ int    st[OUTS];
    __shared__ int    cnt[OUTS];
    __shared__ double plane[INS * INS];          // 32 KB
    __shared__ double hplane[OUTS * INS];        // 10 KB

    int tid = threadIdx.x;
    if (tid < OUTS) {
        double sample = (tid + 0.5) * 3.2 - 0.5;
        int lo = (int)ceil(sample - 3.2);
        int hi = (int)floor(sample + 3.2);
        if (lo < 0) lo = 0;
        if (hi > INS - 1) hi = INS - 1;
        int c = hi - lo + 1;           // <= 7
        double w[8];
        double sum = 0.0;
        for (int k = 0; k < 8; ++k) {
            double ww = 0.0;
            if (k < c) {
                double x = fabs(sample - (double)(lo + k)) * (1.0 / 3.2);
                ww = (x < 1.0) ? (1.0 - x) : 0.0;
            }
            w[k] = ww; sum += ww;
        }
        for (int k = 0; k < 8; ++k) wts[tid][k] = w[k] / sum;
        st[tid] = lo; cnt[tid] = c;
    }
    __syncthreads();

    int od  = blockIdx.x;                        // 0..19
    int c   = blockIdx.y;                        // 0..15
    int sb  = blockIdx.z;                        // 0..3
    int sel = sb >> 1;
    int b   = sb & 1;

    const float* in = (sel ? tgt : src) + (((size_t)(b * CDIM + c)) << 18);

    // ---- d-stage: plane[h][w] = sum_d wd * in[d][h][w], registers ----
    int sd = st[od], cd = cnt[od];
    double acc[16];
#pragma unroll
    for (int i = 0; i < 16; ++i) acc[i] = 0.0;
    for (int t = 0; t < cd; ++t) {
        double wd = wts[od][t];
        const float* p = in + (((size_t)(sd + t)) << 12) + tid;
#pragma unroll
        for (int i = 0; i < 16; ++i)
            acc[i] = fma(wd, (double)p[i << 8], acc[i]);
    }
#pragma unroll
    for (int i = 0; i < 16; ++i) plane[tid + (i << 8)] = acc[i];
    __syncthreads();

    // ---- h-stage: hplane[oh][w] = sum_h wh * plane[h][w] ----
    for (int e = tid; e < OUTS * INS; e += 256) {
        int oh = e >> 6, w = e & 63;
        int sh = st[oh], ch = cnt[oh];
        double a = 0.0;
        for (int t = 0; t < ch; ++t)
            a = fma(wts[oh][t], plane[((sh + t) << 6) + w], a);
        hplane[e] = a;
    }
    __syncthreads();

    // ---- w-stage: out[oh][ow] = sum_w ww * hplane[oh][w] ----
    double* outf = sel ? tfeat : sfeat2;
    for (int e = tid; e < OUTS * OUTS; e += 256) {
        int oh = e / OUTS, ow = e - oh * OUTS;
        int sw = st[ow], cw = cnt[ow];
        const double* hp = &hplane[(oh << 6) + sw];
        double a = 0.0;
        for (int t = 0; t < cw; ++t)
            a = fma(wts[ow][t], hp[t], a);
        if (sel == 0) a = -2.0 * a;              // exact scale
        int n = (od * OUTS + oh) * OUTS + ow;
        outf[((size_t)(b * NPTS + n)) * CDIM + c] = a;
    }
}

__global__ void k_t2(const double* __restrict__ tfeat, double* __restrict__ t2) {
    int i = blockIdx.x * blockDim.x + threadIdx.x;
    if (i >= TOTN) return;
    const double* p = tfeat + (size_t)i * CDIM;
    double a = 0, b = 0, c = 0, d = 0;
#pragma unroll
    for (int k = 0; k < 4; ++k) {
        a = fma(p[4*k+0], p[4*k+0], a);
        b = fma(p[4*k+1], p[4*k+1], b);
        c = fma(p[4*k+2], p[4*k+2], c);
        d = fma(p[4*k+3], p[4*k+3], d);
    }
    t2[i] = (a + b) + (c + d);
}

// f64-MFMA argmin, round-14: dual n-set per wave + SOFTWARE-PIPELINED FOLD.
// Body p+1's MFMAs are issued BEFORE body p's fold, so the fold (VALU)
// overlaps the in-flight MFMA burst instead of waiting out MFMA latency
// between bursts (round-13: MfmaUtil pinned at 50%). Two acc sets (pA/pB);
// fold comparisons unchanged -> bitwise-identical argmin.
__global__ __launch_bounds__(256, 2) void k_argmin(const double* __restrict__ sfeat2,
                                                   const double* __restrict__ tfeat,
                                                   const double* __restrict__ t2,
                                                   double* __restrict__ pscore,
                                                   int* __restrict__ pidx,
                                                   int mchunk, int nchunk) {
    int b     = blockIdx.z;
    int chunk = blockIdx.y;
    int lane  = threadIdx.x & 63;
    int wp    = threadIdx.x >> 6;                // 0..3
    int nbase = blockIdx.x << 7;                 // 128 n per block
    int n0    = nbase + (wp << 4);               // set-0 strip
    int n1    = n0 + 64;                         // set-1 strip (may pad at tail)
    int lr    = lane & 15;                       // fragment feed index
    int lq    = lane >> 4;                       // k-group 0..3

    // ---- layout calibration + pi table ----
    f64x4 z = {0.0, 0.0, 0.0, 0.0};
    f64x4 calA = MFMA64((double)lr, 0.25, z);
    f64x4 calB = MFMA64(0.25, (double)lr, z);
    int ncol = (int)(calB[0] + 0.5);

    __shared__ int ptab[16];
#pragma unroll
    for (int j = 0; j < 4; ++j) {
        int r = (int)(calA[j] + 0.5);            // hardware feed-row of slot j
        ptab[r] = (lq << 2) + j;                 // pi: feed-row -> desired m-offset
    }
    __syncthreads();
    int prow = ptab[lr];                         // A-row permutation for this lane

    // B fragments for both n-sets (k = 4*lq + kb, contiguous 32B per lane)
    int nn0 = n0 + lr; if (nn0 > NPTS - 1) nn0 = NPTS - 1;
    int nn1 = n1 + lr; if (nn1 > NPTS - 1) nn1 = NPTS - 1;
    const double* sb0 = sfeat2 + ((size_t)(b * NPTS + nn0)) * CDIM + (lq << 2);
    const double* sb1 = sfeat2 + ((size_t)(b * NPTS + nn1)) * CDIM + (lq << 2);
    double b00 = sb0[0], b01 = sb0[1], b02 = sb0[2], b03 = sb0[3];
    double b10 = sb1[0], b11 = sb1[1], b12 = sb1[2], b13 = sb1[3];

    const double* tb  = tfeat + (size_t)b * NPTS * CDIM;
    const double* t2b = t2 + (size_t)b * NPTS;

    int mbase = chunk * mchunk;
    int iters = mchunk >> 5;                     // bodies of 32 m (2 tiles)

    const double* tA = tb + ((size_t)(mbase + prow)) * CDIM + (lq << 2);
    const double* tV = t2b + mbase + (lq << 2);

    // per (set, tile) best state
    double bs00 = 1e300, bs01 = 1e300, bs10 = 1e300, bs11 = 1e300;
    int    ip00 = 0, ip01 = 0, ip10 = 0, ip11 = 0;   // body index
    int    ij00 = 0, ij01 = 0, ij10 = 0, ij11 = 0;   // j index

    f64x4 aE0, aE1, vE0, vE1, aO0, aO1, vO0, vO1;    // prefetch buffers
    f64x4 pA0, pA1, pA2, pA3;                        // accs, even body
    f64x4 pB0, pB1, pB2, pB3;                        // accs, odd body

#define LOADP(P, A0, A1, V0, V1)                                   \
    {  const double* pa_ = tA + (size_t)((P) << 5) * CDIM;         \
       A0 = *(const f64x4*)(pa_);                                  \
       A1 = *(const f64x4*)(pa_ + (CDIM << 4));                    \
       const double* pv_ = tV + ((P) << 5);                        \
       V0 = *(const f64x4*)(pv_);                                  \
       V1 = *(const f64x4*)(pv_ + 16); }

    // R0=set0/tile0, R1=set0/tile1, R2=set1/tile0, R3=set1/tile1
#define COMPUTE(A0, A1, V0, V1, R0, R1, R2, R3)                    \
    {  R0 = V0; R1 = V1; R2 = V0; R3 = V1;                         \
       R0 = MFMA64(A0[0], b00, R0);                                \
       R2 = MFMA64(A0[0], b10, R2);                                \
       R1 = MFMA64(A1[0], b00, R1);                                \
       R3 = MFMA64(A1[0], b10, R3);                                \
       R0 = MFMA64(A0[1], b01, R0);                                \
       R2 = MFMA64(A0[1], b11, R2);                                \
       R1 = MFMA64(A1[1], b01, R1);                                \
       R3 = MFMA64(A1[1], b11, R3);                                \
       R0 = MFMA64(A0[2], b02, R0);                                \
       R2 = MFMA64(A0[2], b12, R2);                                \
       R1 = MFMA64(A1[2], b02, R1);                                \
       R3 = MFMA64(A1[2], b12, R3);                                \
       R0 = MFMA64(A0[3], b03, R0);                                \
       R2 = MFMA64(A0[3], b13, R2);                                \
       R1 = MFMA64(A1[3], b03, R1);                                \
       R3 = MFMA64(A1[3], b13, R3); }

#define FOLD(AC, BS, IP, IJ, P)                                    \
    {  double jb_ = AC[0]; int jj_ = 0;                            \
       if (AC[1] < jb_) { jb_ = AC[1]; jj_ = 1; }                  \
       if (AC[2] < jb_) { jb_ = AC[2]; jj_ = 2; }                  \
       if (AC[3] < jb_) { jb_ = AC[3]; jj_ = 3; }                  \
       if (jb_ < BS) { BS = jb_; IP = (P); IJ = jj_; } }

#define FOLD4(R0, R1, R2, R3, P)                                   \
    FOLD(R0, bs00, ip00, ij00, P)                                  \
    FOLD(R1, bs01, ip01, ij01, P)                                  \
    FOLD(R2, bs10, ip10, ij10, P)                                  \
    FOLD(R3, bs11, ip11, ij11, P)

    LOADP(0, aE0, aE1, vE0, vE1);
    if (iters > 1) LOADP(1, aO0, aO1, vO0, vO1);

    COMPUTE(aE0, aE1, vE0, vE1, pA0, pA1, pA2, pA3);       // body 0
    int p = 0;
    for (; p + 2 < iters; p += 2) {
        LOADP(p + 2, aE0, aE1, vE0, vE1);
        COMPUTE(aO0, aO1, vO0, vO1, pB0, pB1, pB2, pB3);   // body p+1
        FOLD4(pA0, pA1, pA2, pA3, p)                        // fold p (overlaps)
        if (p + 3 < iters) LOADP(p + 3, aO0, aO1, vO0, vO1);
        COMPUTE(aE0, aE1, vE0, vE1, pA0, pA1, pA2, pA3);   // body p+2
        FOLD4(pB0, pB1, pB2, pB3, p + 1)                    // fold p+1 (overlaps)
    }
    if (p + 1 < iters) {
        COMPUTE(aO0, aO1, vO0, vO1, pB0, pB1, pB2, pB3);   // last odd body
        FOLD4(pA0, pA1, pA2, pA3, p)
        FOLD4(pB0, pB1, pB2, pB3, p + 1)
    } else {
        FOLD4(pA0, pA1, pA2, pA3, p)
    }

#undef LOADP
#undef COMPUTE
#undef FOLD
#undef FOLD4

    // reconstruct m and fold tiles per set (lexicographic)
    int m00 = mbase + (ip00 << 5) + (lq << 2) + ij00;
    int m01 = mbase + (ip01 << 5) + 16 + (lq << 2) + ij01;
    int m10 = mbase + (ip10 << 5) + (lq << 2) + ij10;
    int m11 = mbase + (ip11 << 5) + 16 + (lq << 2) + ij11;

    double fb0 = bs00; int fm0 = m00;
    if (bs01 < fb0 || (bs01 == fb0 && m01 < fm0)) { fb0 = bs01; fm0 = m01; }
    double fb1 = bs10; int fm1 = m10;
    if (bs11 < fb1 || (bs11 == fb1 && m11 < fm1)) { fb1 = bs11; fm1 = m11; }

    // merge the 4 k-groups holding the same n (lanes l, l^16, l^32, l^48)
#pragma unroll
    for (int off = 16; off <= 32; off <<= 1) {
        double ob = __shfl_xor(fb0, off, 64);
        int    om = __shfl_xor(fm0, off, 64);
        if (ob < fb0 || (ob == fb0 && om < fm0)) { fb0 = ob; fm0 = om; }
        double ob1 = __shfl_xor(fb1, off, 64);
        int    om1 = __shfl_xor(fm1, off, 64);
        if (ob1 < fb1 || (ob1 == fb1 && om1 < fm1)) { fb1 = ob1; fm1 = om1; }
    }
    if (lq == 0) {
        size_t base = ((size_t)(b * nchunk + chunk)) * NPTS;
        int ns0 = n0 + ncol;                     // always < NPTS
        pscore[base + ns0] = fb0;
        pidx[base + ns0]   = fm0;
        int ns1 = n1 + ncol;
        if (ns1 < NPTS) {
            pscore[base + ns1] = fb1;
            pidx[base + ns1]   = fm1;
        }
    }
}

// Merge chunks (ascending, lexicographic) + partial loss.
__global__ void k_mergeloss(const double* __restrict__ pscore,
                            const int* __restrict__ pidx,
                            const float* __restrict__ expd,
                            double* __restrict__ lpart, int nchunk) {
    int gid = blockIdx.x * 256 + threadIdx.x;    // 63*256 = 16128 >= 16000
    double sum = 0.0;
    if (gid < TOTN) {
        int b  = gid / NPTS;
        int nn = gid % NPTS;
        size_t o = ((size_t)(b * nchunk)) * NPTS + nn;
        double b0 = pscore[o];
        int    i0 = pidx[o];
        for (int c = 1; c < nchunk; ++c) {
            double bpv = pscore[o + (size_t)c * NPTS];
            int    ip  = pidx[o + (size_t)c * NPTS];
            if (bpv < b0 || (bpv == b0 && ip < i0)) { b0 = bpv; i0 = ip; }
        }
        double fd = (double)(i0 / 400);
        double fh = (double)((i0 / 20) % 20);
        double fw = (double)(i0 % 20);
        const float* e = expd + (size_t)gid * 3;
        sum = fabs((double)e[0] - fd) + fabs((double)e[1] - fh) + fabs((double)e[2] - fw);
    }
    __shared__ double red[256];
    red[threadIdx.x] = sum;
    __syncthreads();
    for (int s = 128; s > 0; s >>= 1) {
        if (threadIdx.x < s) red[threadIdx.x] += red[threadIdx.x + s];
        __syncthreads();
    }
    if (threadIdx.x == 0) lpart[blockIdx.x] = red[0];
}

__global__ void k_final(const double* __restrict__ lpart, float* __restrict__ out) {
    int lane = threadIdx.x;                      // 64
    double v = (lane < 63) ? lpart[lane] : 0.0;
#pragma unroll
    for (int off = 32; off > 0; off >>= 1) v += __shfl_down(v, off);
    if (lane == 0) out[0] = (float)(v / 48000.0);
}

extern "C" void kernel_launch(void* const* d_in, const int* in_sizes, int n_in,
                              void* d_out, int out_size, void* d_ws, size_t ws_size,
                              hipStream_t stream) {
    const float* src  = (const float*)d_in[0];
    const float* tgt  = (const float*)d_in[1];
    const float* expd = (const float*)d_in[2];

    // nchunk=25 (10 bodies of 32 m) needs ~9.03 MB scratch (proven);
    // fall back to nchunk=5 (50 bodies).
    int nchunk = 25, mchunk = 320;
    {
        size_t need = 4224000ull + (size_t)BDIM * 25 * NPTS * 12 + 512;
        if (ws_size < need) { nchunk = 5; mchunk = 1600; }
    }

    char* ws = (char*)d_ws;
    double* sfeat2 = (double*)(ws);
    double* tfeat  = (double*)(ws + 2048000);
    double* t2     = (double*)(ws + 4096000);
    double* pscore = (double*)(ws + 4224000);
    size_t  psz    = (size_t)BDIM * nchunk * NPTS * 8;
    int*    pidx   = (int*)(ws + 4224000 + psz);
    size_t  isz    = (size_t)BDIM * nchunk * NPTS * 4;
    double* lpart  = (double*)(ws + 4224000 + psz + isz);

    k_resize   <<<dim3(OUTS, CDIM, 4), 256, 0, stream>>>(src, tgt, sfeat2, tfeat);
    k_t2       <<<63, 256, 0, stream>>>(tfeat, t2);
    k_argmin   <<<dim3(63, nchunk, BDIM), 256, 0, stream>>>(sfeat2, tfeat, t2,
                                                            pscore, pidx, mchunk, nchunk);
    k_mergeloss<<<63, 256, 0, stream>>>(pscore, pidx, expd, lpart, nchunk);
    k_final    <<<1, 64, 0, stream>>>(lpart, (float*)d_out);
}